// Round 1
// baseline (2732.074 us; speedup 1.0000x reference)
//
#include <hip/hip_runtime.h>
#include <hip/hip_bf16.h>

#define THREADS 576
#define NWAVES 9

typedef __hip_bfloat16 bf16;
typedef __attribute__((ext_vector_type(4))) float f32x4;
typedef __attribute__((ext_vector_type(8))) short bf16x8;

#define MFMA16x16x32 __builtin_amdgcn_mfma_f32_16x16x32_bf16

// ---- LDS layout (bf16 element offsets). Block = 512 bf16 = one 16(M/N)x32(K) fragment tile.
#define O_WL1 0       // LSTM1 B: 4 nt x 1 kc
#define O_WF1 2048    // FC1  B: 4 x 2
#define O_WF2 6144    // FC2  B: 5 x 2
#define O_WL3 11264   // LSTM3 B: 8 x 4
#define O_WF3 27648   // FC3  B: 1 x 1
#define O_WF4 28160   // FC4  B: 1 x 1
#define O_A1  28672   // [xt(2)|h1(16)|pad] : 4 mt x 1 kc
#define O_AY  30720   // yt: 4 x 2
#define O_AT1 34816   // t1 / u: 4 x 2
#define O_A2  38912   // [l2(72)|h2(72)|pad16]: 4 x 5
#define O_A3  49152   // [h1|h2|h3|pad8]: 4 x 4
#define O_AF3 57344   // h3: 4 x 1
#define O_GB  59392   // gate buffer, row-major bf16, max 64x288
#define BF16_TOTAL 77824
#define BIAS_BYTE_OFF (BF16_TOTAL * 2)
// bias float offsets within bias region
#define B_L1 0
#define B_F1 64
#define B_F2 128
#define B_L2 200
#define B_L3 488
#define B_F3 616
#define B_F4 632
#define LDS_BYTES (BF16_TOTAL * 2 + 640 * 4)

// assumed (self-consistent) K mapping within a 16x32 fragment tile
__device__ __forceinline__ int kmap(int l, int j) {
    return (((l >> 4) & 3) << 2) + (j & 3) + ((j >> 2) << 4);
}
__device__ __forceinline__ int frag_idx(int m, int k) { // k in [0,32)
    int l = (m & 15) | (((k >> 2) & 3) << 4);
    int j = (k & 3) | (((k >> 4) & 1) << 2);
    return (l << 3) + j;
}
__device__ __forceinline__ void st_frag(bf16* sbase, int KC, int m, int k, float v) {
    sbase[(((m >> 4) * KC + (k >> 5)) << 9) + frag_idx(m, k & 31)] = __float2bfloat16(v);
}

__device__ __forceinline__ float sigm(float x) { return 1.0f / (1.0f + __expf(-x)); }
__device__ __forceinline__ float tanh_(float x) {
    float e = __expf(2.0f * fminf(x, 44.0f));
    return (e - 1.0f) / (e + 1.0f);
}

template <typename EPI>
__device__ __forceinline__ void gemm(const bf16* __restrict__ A, const bf16* __restrict__ B,
                                     int TM, int TN, int KCbufA, int KCrun,
                                     int wave, int lane, EPI epi) {
    for (int tile = wave; tile < TM * TN; tile += NWAVES) {
        int mt = tile / TN, nt = tile - mt * TN;
        f32x4 acc = {0.f, 0.f, 0.f, 0.f};
        for (int kc = 0; kc < KCrun; ++kc) {
            bf16x8 a = *(const bf16x8*)(A + ((mt * KCbufA + kc) << 9) + (lane << 3));
            bf16x8 b = *(const bf16x8*)(B + ((nt * KCrun + kc) << 9) + (lane << 3));
            acc = MFMA16x16x32(a, b, acc, 0, 0, 0);
        }
        epi(acc, mt, nt);
    }
}

template <int H, int MAXIT, typename WR>
__device__ __forceinline__ void lstm_ew(const bf16* __restrict__ g, float* creg, int tid, WR wr) {
#pragma unroll
    for (int it = 0; it < MAXIT; ++it) {
        int item = tid + it * THREADS;
        if (item < 64 * H) {
            int m = item / H, h = item - m * H;
            const bf16* row = g + m * 4 * H;
            float ig = sigm(__bfloat162float(row[h]));
            float fg = sigm(__bfloat162float(row[H + h]));
            float gg = tanh_(__bfloat162float(row[2 * H + h]));
            float og = sigm(__bfloat162float(row[3 * H + h]));
            float c = fg * creg[it] + ig * gg;
            creg[it] = c;
            wr(m, h, og * tanh_(c));
        }
    }
}

__global__ void __launch_bounds__(THREADS)
lstm_fused(const float* __restrict__ x, const float* __restrict__ y,
           const float* __restrict__ Wih1, const float* __restrict__ Whh1,
           const float* __restrict__ bih1, const float* __restrict__ bhh1,
           const float* __restrict__ Wih2, const float* __restrict__ Whh2,
           const float* __restrict__ bih2, const float* __restrict__ bhh2,
           const float* __restrict__ Wih3, const float* __restrict__ Whh3,
           const float* __restrict__ bih3, const float* __restrict__ bhh3,
           const float* __restrict__ W1, const float* __restrict__ b1,
           const float* __restrict__ W2, const float* __restrict__ b2,
           const float* __restrict__ W3, const float* __restrict__ b3,
           const float* __restrict__ W4, const float* __restrict__ b4,
           float* __restrict__ out) {
    extern __shared__ char smem_raw[];
    bf16* sb = (bf16*)smem_raw;
    float* sbias = (float*)(smem_raw + BIAS_BYTE_OFF);
    const int tid = threadIdx.x;
    const int wave = tid >> 6, lane = tid & 63;
    const int b0 = blockIdx.x * 64;

    // ---- build bf16 weight buffers in LDS (zero-padded) ----
    auto build = [&](int dstOff, int TN, int KC, auto src) {
        bf16* dst = sb + dstOff;
        int tot = TN * KC * 512;
        for (int idx = tid; idx < tot; idx += THREADS) {
            int blk = idx >> 9, w = idx & 511;
            int l = w >> 3, j = w & 7;
            int nt = blk / KC, kc = blk - nt * KC;
            int n = (nt << 4) + (l & 15);
            int k = (kc << 5) + kmap(l, j);
            dst[idx] = __float2bfloat16(src(n, k));
        }
    };
    build(O_WL1, 4, 1, [&](int n, int k) {
        return k < 2 ? Wih1[n * 2 + k] : (k < 18 ? Whh1[n * 16 + (k - 2)] : 0.0f); });
    build(O_WF1, 4, 2, [&](int n, int k) { return k < 36 ? W1[n * 36 + k] : 0.0f; });
    build(O_WF2, 5, 2, [&](int n, int k) { return (n < 72) ? W2[n * 64 + k] : 0.0f; });
    build(O_WL3, 8, 4, [&](int n, int k) {
        return k < 88 ? Wih3[n * 88 + k] : (k < 120 ? Whh3[n * 32 + (k - 88)] : 0.0f); });
    build(O_WF3, 1, 1, [&](int n, int k) { return W3[n * 32 + k]; });
    build(O_WF4, 1, 1, [&](int n, int k) { return (n < 2 && k < 16) ? W4[n * 16 + k] : 0.0f; });

    // biases (pre-summed ih+hh for LSTMs)
    if (tid < 64) { sbias[B_L1 + tid] = bih1[tid] + bhh1[tid]; sbias[B_F1 + tid] = b1[tid]; }
    if (tid < 72) sbias[B_F2 + tid] = b2[tid];
    if (tid < 288) sbias[B_L2 + tid] = bih2[tid] + bhh2[tid];
    if (tid < 128) sbias[B_L3 + tid] = bih3[tid] + bhh3[tid];
    if (tid < 16) sbias[B_F3 + tid] = b3[tid];
    if (tid < 2) sbias[B_F4 + tid] = b4[tid];

    // zero all activation fragment buffers (covers initial h-state + all pads)
    for (int i = O_A1 + tid; i < O_GB; i += THREADS) sb[i] = __float2bfloat16(0.0f);

    // ---- LSTM2 B fragments in registers: wave owns N-tiles {2*wave, 2*wave+1} ----
    bf16x8 b2f[2][5];
#pragma unroll
    for (int ntl = 0; ntl < 2; ++ntl) {
        int n = ((wave * 2 + ntl) << 4) + (lane & 15);
#pragma unroll
        for (int kc = 0; kc < 5; ++kc) {
            union { bf16x8 v; bf16 h[8]; } u;
#pragma unroll
            for (int j = 0; j < 8; ++j) {
                int k = kc * 32 + kmap(lane, j);
                float val = 0.0f;
                if (k < 72) val = Wih2[n * 72 + k];
                else if (k < 144) val = Whh2[n * 72 + (k - 72)];
                u.h[j] = __float2bfloat16(val);
            }
            b2f[ntl][kc] = u.v;
        }
    }

    float c1r[2] = {0.f, 0.f};
    float c2r[8] = {0.f, 0.f, 0.f, 0.f, 0.f, 0.f, 0.f, 0.f};
    float c3r[4] = {0.f, 0.f, 0.f, 0.f};

    __syncthreads();

    for (int t = 0; t < 25; ++t) {
        // P0: stage xt -> A1[k<2], yt -> AY
        if (tid < 128) {
            int m = tid >> 1, k = tid & 1;
            st_frag(sb + O_A1, 1, m, k, x[(size_t)(b0 + m) * 50 + t * 2 + k]);
        }
        for (int it = tid; it < 64 * 36; it += THREADS) {
            int m = it / 36, k = it - m * 36;
            st_frag(sb + O_AY, 2, m, k, y[(size_t)(b0 + m) * 900 + t * 36 + k]);
        }
        __syncthreads();

        // P1: LSTM1 gates -> GB (stride 64); FC1 -> relu -> AT1
        gemm(sb + O_A1, sb + O_WL1, 4, 4, 1, 1, wave, lane, [&](f32x4 acc, int mt, int nt) {
            int n = (nt << 4) + (lane & 15);
            int mrow = (mt << 4) + ((lane >> 4) << 2);
            float bias = sbias[B_L1 + n];
#pragma unroll
            for (int r = 0; r < 4; ++r)
                sb[O_GB + (mrow + r) * 64 + n] = __float2bfloat16(acc[r] + bias);
        });
        gemm(sb + O_AY, sb + O_WF1, 4, 4, 2, 2, wave, lane, [&](f32x4 acc, int mt, int nt) {
            int n = (nt << 4) + (lane & 15);
            int mrow = (mt << 4) + ((lane >> 4) << 2);
            float bias = sbias[B_F1 + n];
#pragma unroll
            for (int r = 0; r < 4; ++r)
                st_frag(sb + O_AT1, 2, mrow + r, n, fmaxf(acc[r] + bias, 0.0f));
        });
        __syncthreads();

        // P2: FC2 (t1 -> l2 into A2[k<72]) ; EW1 (h1 -> A1[k=2+h], A3[k=h])
        gemm(sb + O_AT1, sb + O_WF2, 4, 5, 2, 2, wave, lane, [&](f32x4 acc, int mt, int nt) {
            int n = (nt << 4) + (lane & 15);
            if (n < 72) {
                int mrow = (mt << 4) + ((lane >> 4) << 2);
                float bias = sbias[B_F2 + n];
#pragma unroll
                for (int r = 0; r < 4; ++r)
                    st_frag(sb + O_A2, 5, mrow + r, n, acc[r] + bias);
            }
        });
        lstm_ew<16, 2>(sb + O_GB, c1r, tid, [&](int m, int h, float v) {
            st_frag(sb + O_A1, 1, m, 2 + h, v);
            st_frag(sb + O_A3, 4, m, h, v);
        });
        __syncthreads();

        // P3: LSTM2 gates (B from registers) -> GB stride 288
#pragma unroll
        for (int ntl = 0; ntl < 2; ++ntl) {
            int nt = wave * 2 + ntl;
            int n = (nt << 4) + (lane & 15);
            float bias = sbias[B_L2 + n];
            for (int mt = 0; mt < 4; ++mt) {
                f32x4 acc = {0.f, 0.f, 0.f, 0.f};
#pragma unroll
                for (int kc = 0; kc < 5; ++kc) {
                    bf16x8 a = *(const bf16x8*)(sb + O_A2 + ((mt * 5 + kc) << 9) + (lane << 3));
                    acc = MFMA16x16x32(a, b2f[ntl][kc], acc, 0, 0, 0);
                }
                int mrow = (mt << 4) + ((lane >> 4) << 2);
#pragma unroll
                for (int r = 0; r < 4; ++r)
                    sb[O_GB + (mrow + r) * 288 + n] = __float2bfloat16(acc[r] + bias);
            }
        }
        __syncthreads();

        // P4: EW2 (h2 -> A2[k=72+h], A3[k=16+h])
        lstm_ew<72, 8>(sb + O_GB, c2r, tid, [&](int m, int h, float v) {
            st_frag(sb + O_A2, 5, m, 72 + h, v);
            st_frag(sb + O_A3, 4, m, 16 + h, v);
        });
        __syncthreads();

        // P5: LSTM3 gates -> GB stride 128
        gemm(sb + O_A3, sb + O_WL3, 4, 8, 4, 4, wave, lane, [&](f32x4 acc, int mt, int nt) {
            int n = (nt << 4) + (lane & 15);
            int mrow = (mt << 4) + ((lane >> 4) << 2);
            float bias = sbias[B_L3 + n];
#pragma unroll
            for (int r = 0; r < 4; ++r)
                sb[O_GB + (mrow + r) * 128 + n] = __float2bfloat16(acc[r] + bias);
        });
        __syncthreads();

        // P6: EW3 (h3 -> A3[k=88+h], AF3[k=h])
        lstm_ew<32, 4>(sb + O_GB, c3r, tid, [&](int m, int h, float v) {
            st_frag(sb + O_A3, 4, m, 88 + h, v);
            st_frag(sb + O_AF3, 1, m, h, v);
        });
        __syncthreads();

        // P7: FC3: u = relu(h3 W3^T + b3) -> AT1 chunk0 (k16..31 stale, killed by B zeros)
        gemm(sb + O_AF3, sb + O_WF3, 4, 1, 1, 1, wave, lane, [&](f32x4 acc, int mt, int nt) {
            int n = (nt << 4) + (lane & 15);
            int mrow = (mt << 4) + ((lane >> 4) << 2);
            float bias = sbias[B_F3 + n];
#pragma unroll
            for (int r = 0; r < 4; ++r)
                st_frag(sb + O_AT1, 2, mrow + r, n, fmaxf(acc[r] + bias, 0.0f));
        });
        __syncthreads();

        // P8: FC4 -> global out
        gemm(sb + O_AT1, sb + O_WF4, 4, 1, 2, 1, wave, lane, [&](f32x4 acc, int mt, int nt) {
            int n = lane & 15;
            if (n < 2) {
                int mrow = (mt << 4) + ((lane >> 4) << 2);
                float bias = sbias[B_F4 + n];
#pragma unroll
                for (int r = 0; r < 4; ++r)
                    out[(size_t)(b0 + mrow + r) * 50 + t * 2 + n] = acc[r] + bias;
            }
        });
        __syncthreads();
    }
}

extern "C" void kernel_launch(void* const* d_in, const int* in_sizes, int n_in,
                              void* d_out, int out_size, void* d_ws, size_t ws_size,
                              hipStream_t stream) {
    (void)in_sizes; (void)n_in; (void)d_ws; (void)ws_size; (void)out_size;
    hipFuncSetAttribute((const void*)lstm_fused,
                        hipFuncAttributeMaxDynamicSharedMemorySize, LDS_BYTES);
    lstm_fused<<<dim3(2048), dim3(THREADS), LDS_BYTES, stream>>>(
        (const float*)d_in[0], (const float*)d_in[1],
        (const float*)d_in[2], (const float*)d_in[3],
        (const float*)d_in[4], (const float*)d_in[5],
        (const float*)d_in[6], (const float*)d_in[7],
        (const float*)d_in[8], (const float*)d_in[9],
        (const float*)d_in[10], (const float*)d_in[11],
        (const float*)d_in[12], (const float*)d_in[13],
        (const float*)d_in[14], (const float*)d_in[15],
        (const float*)d_in[16], (const float*)d_in[17],
        (const float*)d_in[18], (const float*)d_in[19],
        (const float*)d_in[20], (const float*)d_in[21],
        (float*)d_out);
}

// Round 2
// 1898.662 us; speedup vs baseline: 1.4389x; 1.4389x over previous
//
#include <hip/hip_runtime.h>
#include <hip/hip_bf16.h>

#define THREADS 576

typedef __hip_bfloat16 bf16;
typedef __attribute__((ext_vector_type(4))) float f32x4;
typedef __attribute__((ext_vector_type(8))) short bf16x8;

#define MFMA __builtin_amdgcn_mfma_f32_16x16x32_bf16

// ---- LDS layout (bf16 element offsets), blocks of 512 = one 16x32 fragment tile
#define O_A1  0       // [buf0|buf1] x 4mt x 1kc : [x(2)|h1(16)|pad]
#define O_AY  4096    // 4mt x 2kc : [y(36)|pad]
#define O_AT1 8192    // 4mt x 2kc : t1(64)
#define O_A2  12288   // 4mt x 9kc : [l2(72)|pad | h2slot0(3kc) | h2slot1(3kc)]
#define O_A3  30720   // 4mt x 5kc : [h1(16)|h2(72)|pad | h3slot0(1kc) | h3slot1(1kc)]
#define LDS_ELEMS 40960
#define LDS_BYTES (LDS_ELEMS * 2)   // 81920

// self-consistent K mapping within a 16x32 fragment tile (verified round 1)
__device__ __forceinline__ int kmap(int l, int j) {
    return (((l >> 4) & 3) << 2) + (j & 3) + ((j >> 2) << 4);
}
__device__ __forceinline__ int frag_off(int m, int k) { // k in [0,32)
    int l = (m & 15) | (((k >> 2) & 3) << 4);
    int j = (k & 3) | (((k >> 4) & 1) << 2);
    return (l << 3) + j;
}
__device__ __forceinline__ void st_frag(bf16* sbase, int KC, int m, int k, float v) {
    sbase[(((m >> 4) * KC + (k >> 5)) << 9) + frag_off(m, k & 31)] = __float2bfloat16(v);
}

__device__ __forceinline__ float rcp_(float x) { return __builtin_amdgcn_rcpf(x); }
__device__ __forceinline__ float sigm(float x) { return rcp_(1.0f + __expf(-x)); }
__device__ __forceinline__ float tanh_(float x) { return 1.0f - 2.0f * rcp_(1.0f + __expf(2.0f * x)); }

__device__ __forceinline__ float pick4(float a, float b, float c, float d, int j) {
    float ab = (j & 1) ? b : a;
    float cd = (j & 1) ? d : c;
    return (j & 2) ? cd : ab;
}

__device__ __forceinline__ ushort bfu(float f) {
    union { bf16 b; ushort u; } v; v.b = __float2bfloat16(f); return v.u;
}

// fused gate-EW for interleaved-gate tiles: col n = h*4+g ; lane handles row r*=g
template <typename WR>
__device__ __forceinline__ void lstm_tile_ew(f32x4 acc, float bias, float& cst, int lane, WR wr) {
    int g = lane & 3;
    float a0 = acc[0] + bias, a1 = acc[1] + bias, a2 = acc[2] + bias, a3 = acc[3] + bias;
    float own = pick4(a0, a1, a2, a3, g);
    float p1 = pick4(a0, a1, a2, a3, g ^ 1);
    float p2 = pick4(a0, a1, a2, a3, g ^ 2);
    float p3 = pick4(a0, a1, a2, a3, g ^ 3);
    float q1 = __shfl_xor(p1, 1, 64);
    float q2 = __shfl_xor(p2, 2, 64);
    float q3 = __shfl_xor(p3, 3, 64);
    float iv = pick4(own, q1, q2, q3, g);
    float fv = pick4(own, q1, q2, q3, g ^ 1);
    float gv = pick4(own, q1, q2, q3, g ^ 2);
    float ov = pick4(own, q1, q2, q3, g ^ 3);
    float c = sigm(fv) * cst + sigm(iv) * tanh_(gv);
    cst = c;
    wr(sigm(ov) * tanh_(c));
}

template <typename F>
__device__ __forceinline__ bf16x8 mk_frag(int lane, int kc, F val) {
    union { bf16x8 v; bf16 h[8]; } u;
#pragma unroll
    for (int j = 0; j < 8; ++j) {
        int k = kc * 32 + kmap(lane, j);
        u.h[j] = __float2bfloat16(val(k));
    }
    return u.v;
}

__global__ void __launch_bounds__(THREADS)
lstm_fused(const float* __restrict__ x, const float* __restrict__ y,
           const float* __restrict__ Wih1, const float* __restrict__ Whh1,
           const float* __restrict__ bih1, const float* __restrict__ bhh1,
           const float* __restrict__ Wih2, const float* __restrict__ Whh2,
           const float* __restrict__ bih2, const float* __restrict__ bhh2,
           const float* __restrict__ Wih3, const float* __restrict__ Whh3,
           const float* __restrict__ bih3, const float* __restrict__ bhh3,
           const float* __restrict__ W1, const float* __restrict__ b1,
           const float* __restrict__ W2, const float* __restrict__ b2,
           const float* __restrict__ W3, const float* __restrict__ b3,
           const float* __restrict__ W4, const float* __restrict__ b4,
           float* __restrict__ out) {
    extern __shared__ char smem[];
    bf16* sb = (bf16*)smem;
    const int tid = threadIdx.x;
    const int wave = tid >> 6, lane = tid & 63, ln15 = lane & 15;
    const int b0 = blockIdx.x * 64;

    // ---- per-wave register-resident B fragments + biases ----
    bf16x8 bL1 = {};  float biasL1 = 0.f;
    bf16x8 bF1[2] = {}; float biasF1 = 0.f;
    bf16x8 bF2[2] = {}; float biasF2 = 0.f;
    bf16x8 bL2[2][6]; float biasL2[2];
    bf16x8 bL3[4] = {}; float biasL3 = 0.f;
    bf16x8 bF3 = {};  float biasF3 = 0.f, w40 = 0.f, w41 = 0.f, b40 = 0.f, b41 = 0.f;

    if (wave < 4) { // LSTM1 gates interleaved: nt=wave, H=16
        int n = (wave << 4) + ln15;
        int r = (n & 3) * 16 + (n >> 2);
        biasL1 = bih1[r] + bhh1[r];
        bL1 = mk_frag(lane, 0, [&](int k) {
            return k < 2 ? Wih1[r * 2 + k] : (k < 18 ? Whh1[r * 16 + (k - 2)] : 0.0f); });
    }
    if (wave >= 4 && wave < 8) { // FC1: nt=wave-4
        int n = ((wave - 4) << 4) + ln15;
        biasF1 = b1[n];
#pragma unroll
        for (int kc = 0; kc < 2; ++kc)
            bF1[kc] = mk_frag(lane, kc, [&](int k) { return k < 36 ? W1[n * 36 + k] : 0.0f; });
    }
    if (wave < 5) { // FC2: nt=wave, 72 cols
        int n = (wave << 4) + ln15;
        biasF2 = (n < 72) ? b2[n] : 0.0f;
#pragma unroll
        for (int kc = 0; kc < 2; ++kc)
            bF2[kc] = mk_frag(lane, kc, [&](int k) { return (n < 72) ? W2[n * 64 + k] : 0.0f; });
    }
#pragma unroll
    for (int ntl = 0; ntl < 2; ++ntl) { // LSTM2 interleaved: nt = wave + ntl*9, H=72
        int n = ((wave + ntl * 9) << 4) + ln15;
        int r = (n & 3) * 72 + (n >> 2);
        biasL2[ntl] = bih2[r] + bhh2[r];
#pragma unroll
        for (int b = 0; b < 6; ++b)
            bL2[ntl][b] = mk_frag(lane, b, [&](int k) {
                return k < 72 ? Wih2[r * 72 + k]
                              : ((k >= 96 && k < 168) ? Whh2[r * 72 + (k - 96)] : 0.0f); });
    }
    if (wave < 8) { // LSTM3 interleaved: nt=wave, H=32; K: [h1|h2|pad|h3]
        int n = (wave << 4) + ln15;
        int r = (n & 3) * 32 + (n >> 2);
        biasL3 = bih3[r] + bhh3[r];
#pragma unroll
        for (int b = 0; b < 4; ++b)
            bL3[b] = mk_frag(lane, b, [&](int k) {
                return k < 88 ? Wih3[r * 88 + k]
                              : ((k >= 96 && k < 128) ? Whh3[r * 32 + (k - 96)] : 0.0f); });
    }
    if (wave < 4) { // FC3 (mt=wave, shared nt=0) + FC4 scalars
        int n = ln15;
        biasF3 = b3[n]; w40 = W4[n]; w41 = W4[16 + n];
        b40 = b4[0]; b41 = b4[1];
        bF3 = mk_frag(lane, 0, [&](int k) { return W3[n * 32 + k]; });
    }

    // ---- zero LDS ----
    {
        int4* z = (int4*)sb;
        int4 zv = {0, 0, 0, 0};
        for (int i = tid; i < LDS_BYTES / 16; i += THREADS) z[i] = zv;
    }
    __syncthreads();
    // ---- stage x(0), y(0) ----
    if (tid < 128) {
        int m = tid >> 1, k = tid & 1;
        st_frag(sb + O_A1, 1, m, k, x[(size_t)(b0 + m) * 50 + k]);
    }
    for (int it = tid; it < 64 * 36; it += THREADS) {
        int m = it / 36, k = it - m * 36;
        st_frag(sb + O_AY, 2, m, k, y[(size_t)(b0 + m) * 900 + k]);
    }
    float c1[4] = {0.f, 0.f, 0.f, 0.f};
    float c2[2][4] = {{0.f, 0.f, 0.f, 0.f}, {0.f, 0.f, 0.f, 0.f}};
    float c3[4] = {0.f, 0.f, 0.f, 0.f};
    ushort4 ypk[9]; uint xpk = 0;
    __syncthreads();

    for (int t = 0; t < 25; ++t) {
        const int rs = t & 1, ws = rs ^ 1;

        // ---- P1: LSTM1 (waves 0-3) | FC1 (waves 4-7) | y/x(t+1) load (wave 8) ----
        if (wave < 4) {
            const bf16* A = sb + O_A1 + ((rs * 4) << 9);
#pragma unroll
            for (int mt = 0; mt < 4; ++mt) {
                bf16x8 a = *(const bf16x8*)(A + (mt << 9) + (lane << 3));
                f32x4 acc = {0.f, 0.f, 0.f, 0.f};
                acc = MFMA(a, bL1, acc, 0, 0, 0);
                lstm_tile_ew(acc, biasL1, c1[mt], lane, [&](float hv) {
                    int m = (mt << 4) + ((lane >> 4) << 2) + (lane & 3);
                    int h = (wave << 2) + ((lane >> 2) & 3);
                    st_frag(sb + O_A1 + ((ws * 4) << 9), 1, m, 2 + h, hv);
                    st_frag(sb + O_A3, 5, m, h, hv);
                });
            }
        } else if (wave < 8) {
            const int nt = wave - 4;
#pragma unroll
            for (int mt = 0; mt < 4; ++mt) {
                f32x4 acc = {0.f, 0.f, 0.f, 0.f};
#pragma unroll
                for (int kc = 0; kc < 2; ++kc) {
                    bf16x8 a = *(const bf16x8*)(sb + O_AY + ((mt * 2 + kc) << 9) + (lane << 3));
                    acc = MFMA(a, bF1[kc], acc, 0, 0, 0);
                }
                int n = (nt << 4) + ln15;
                int mrow = (mt << 4) + ((lane >> 4) << 2);
#pragma unroll
                for (int r = 0; r < 4; ++r)
                    st_frag(sb + O_AT1, 2, mrow + r, n, fmaxf(acc[r] + biasF1, 0.0f));
            }
        } else if (t < 24) {
            const float* yp = y + (size_t)(b0 + lane) * 900 + (t + 1) * 36;
            float4 yv[9];
#pragma unroll
            for (int c = 0; c < 9; ++c) yv[c] = *(const float4*)(yp + c * 4);
            float2 xv = *(const float2*)(x + (size_t)(b0 + lane) * 50 + (t + 1) * 2);
#pragma unroll
            for (int c = 0; c < 9; ++c) {
                ypk[c].x = bfu(yv[c].x); ypk[c].y = bfu(yv[c].y);
                ypk[c].z = bfu(yv[c].z); ypk[c].w = bfu(yv[c].w);
            }
            union { uint u; ushort s[2]; } xu;
            xu.s[0] = bfu(xv.x); xu.s[1] = bfu(xv.y);
            xpk = xu.u;
        }
        __syncthreads();

        // ---- P2: FC2 (waves 0-4) | staged ds_writes (wave 8) ----
        if (wave < 5) {
#pragma unroll
            for (int mt = 0; mt < 4; ++mt) {
                f32x4 acc = {0.f, 0.f, 0.f, 0.f};
#pragma unroll
                for (int kc = 0; kc < 2; ++kc) {
                    bf16x8 a = *(const bf16x8*)(sb + O_AT1 + ((mt * 2 + kc) << 9) + (lane << 3));
                    acc = MFMA(a, bF2[kc], acc, 0, 0, 0);
                }
                int n = (wave << 4) + ln15;
                if (n < 72) {
                    int mrow = (mt << 4) + ((lane >> 4) << 2);
#pragma unroll
                    for (int r = 0; r < 4; ++r)
                        st_frag(sb + O_A2, 9, mrow + r, n, acc[r] + biasF2);
                }
            }
        } else if (wave == 8 && t < 24) {
            const int m = lane, mt = m >> 4;
#pragma unroll
            for (int c = 0; c < 9; ++c) {
                int k0 = 4 * c;
                int l2v = (m & 15) | (((k0 >> 2) & 3) << 4);
                int j0 = ((k0 >> 4) & 1) << 2;
                ushort* dst = (ushort*)(sb + O_AY) + (((mt * 2 + (k0 >> 5)) << 9) + (l2v << 3) + j0);
                *(ushort4*)dst = ypk[c];
            }
            *(uint*)((ushort*)(sb + O_A1) + (((ws * 4 + mt) << 9) + ((m & 15) << 3))) = xpk;
        }
        __syncthreads();

        // ---- P3: LSTM2 (all 9 waves) ----
#pragma unroll
        for (int ntl = 0; ntl < 2; ++ntl) {
            const int nt = wave + ntl * 9;
#pragma unroll
            for (int mt = 0; mt < 4; ++mt) {
                f32x4 acc = {0.f, 0.f, 0.f, 0.f};
#pragma unroll
                for (int b = 0; b < 6; ++b) {
                    int kcA = (b < 3) ? b : b + 3 * rs;
                    bf16x8 a = *(const bf16x8*)(sb + O_A2 + ((mt * 9 + kcA) << 9) + (lane << 3));
                    acc = MFMA(a, bL2[ntl][b], acc, 0, 0, 0);
                }
                lstm_tile_ew(acc, biasL2[ntl], c2[ntl][mt], lane, [&](float hv) {
                    int m = (mt << 4) + ((lane >> 4) << 2) + (lane & 3);
                    int h = (nt << 2) + ((lane >> 2) & 3);
                    st_frag(sb + O_A2, 9, m, (3 + 3 * ws) * 32 + h, hv);
                    st_frag(sb + O_A3, 5, m, 16 + h, hv);
                });
            }
        }
        __syncthreads();

        // ---- P4: LSTM3 (waves 0-7) ----
        if (wave < 8) {
#pragma unroll
            for (int mt = 0; mt < 4; ++mt) {
                f32x4 acc = {0.f, 0.f, 0.f, 0.f};
#pragma unroll
                for (int b = 0; b < 4; ++b) {
                    int kcA = (b < 3) ? b : 3 + rs;
                    bf16x8 a = *(const bf16x8*)(sb + O_A3 + ((mt * 5 + kcA) << 9) + (lane << 3));
                    acc = MFMA(a, bL3[b], acc, 0, 0, 0);
                }
                lstm_tile_ew(acc, biasL3, c3[mt], lane, [&](float hv) {
                    int m = (mt << 4) + ((lane >> 4) << 2) + (lane & 3);
                    int h = (wave << 2) + ((lane >> 2) & 3);
                    st_frag(sb + O_A3, 5, m, (3 + ws) * 32 + h, hv);
                });
            }
        }
        __syncthreads();

        // ---- P5: FC3 + FC4 (waves 0-3, mt=wave) ----
        if (wave < 4) {
            const int mt = wave;
            bf16x8 a = *(const bf16x8*)(sb + O_A3 + ((mt * 5 + 3 + ws) << 9) + (lane << 3));
            f32x4 acc = {0.f, 0.f, 0.f, 0.f};
            acc = MFMA(a, bF3, acc, 0, 0, 0);
            f32x4 s0, s1;
#pragma unroll
            for (int r = 0; r < 4; ++r) {
                float u = fmaxf(acc[r] + biasF3, 0.0f);
                s0[r] = u * w40; s1[r] = u * w41;
            }
#pragma unroll
            for (int msk = 1; msk < 16; msk <<= 1) {
#pragma unroll
                for (int r = 0; r < 4; ++r) {
                    s0[r] += __shfl_xor(s0[r], msk, 64);
                    s1[r] += __shfl_xor(s1[r], msk, 64);
                }
            }
            if (ln15 == 0) {
                int mrow = (mt << 4) + ((lane >> 4) << 2);
#pragma unroll
                for (int r = 0; r < 4; ++r) {
                    float2 o; o.x = s0[r] + b40; o.y = s1[r] + b41;
                    *(float2*)(out + (size_t)(b0 + mrow + r) * 50 + t * 2) = o;
                }
            }
        }
        __syncthreads();
    }
}

extern "C" void kernel_launch(void* const* d_in, const int* in_sizes, int n_in,
                              void* d_out, int out_size, void* d_ws, size_t ws_size,
                              hipStream_t stream) {
    (void)in_sizes; (void)n_in; (void)d_ws; (void)ws_size; (void)out_size;
    hipFuncSetAttribute((const void*)lstm_fused,
                        hipFuncAttributeMaxDynamicSharedMemorySize, LDS_BYTES);
    lstm_fused<<<dim3(2048), dim3(THREADS), LDS_BYTES, stream>>>(
        (const float*)d_in[0], (const float*)d_in[1],
        (const float*)d_in[2], (const float*)d_in[3],
        (const float*)d_in[4], (const float*)d_in[5],
        (const float*)d_in[6], (const float*)d_in[7],
        (const float*)d_in[8], (const float*)d_in[9],
        (const float*)d_in[10], (const float*)d_in[11],
        (const float*)d_in[12], (const float*)d_in[13],
        (const float*)d_in[14], (const float*)d_in[15],
        (const float*)d_in[16], (const float*)d_in[17],
        (const float*)d_in[18], (const float*)d_in[19],
        (const float*)d_in[20], (const float*)d_in[21],
        (float*)d_out);
}